// Round 1
// baseline (1349.671 us; speedup 1.0000x reference)
//
#include <hip/hip_runtime.h>
#include <hip/hip_bf16.h>

// out_b = ||x_b||^2 * (x_b . rho . x_b^T),  B = 4194304, D = 64, fp32.
//
// Strategy: Y = X * S (S = symmetrized rho, bf16 MFMA 16x16x32), then
// quad_b = dot(x_b, y_b) and norm2_b = dot(x_b, x_b) in fp32.
// One wave per 16-row tile; rho fragments live in registers for the whole
// kernel; X read once from HBM (A-fragments) + once via L1 (dot re-read).

typedef __bf16 bf16x8 __attribute__((ext_vector_type(8)));
typedef float  f32x4  __attribute__((ext_vector_type(4)));

#define DIM 64

__global__ __launch_bounds__(256, 4)
void qim_kernel(const float* __restrict__ x,
                const float* __restrict__ rho,
                float* __restrict__ out,
                int ntiles)
{
    const int lane = threadIdx.x & 63;
    const int wid  = threadIdx.x >> 6;   // wave in block: 0..3
    const int l15  = lane & 15;
    const int quad = lane >> 4;          // 0..3

    // ---- rho B-fragments, held in registers for the whole kernel ----
    // B-frag (16x16x32): lane holds B[k][n] with n = l15 (+16*t), k = quad*8+j (+32*h).
    // Use S = (rho + rho^T)/2: exact for the quadratic form, and S = S^T makes
    // the result invariant to any A/B fragment-transpose mixup.
    bf16x8 bfrag[4][2];
    #pragma unroll
    for (int t = 0; t < 4; ++t) {
        #pragma unroll
        for (int h = 0; h < 2; ++h) {
            const int n  = t * 16 + l15;
            const int k0 = h * 32 + quad * 8;
            bf16x8 f;
            #pragma unroll
            for (int j = 0; j < 8; ++j) {
                const int k = k0 + j;
                float s = 0.5f * (rho[k * DIM + n] + rho[n * DIM + k]);
                f[j] = (__bf16)s;
            }
            bfrag[t][h] = f;
        }
    }

    const int gw = blockIdx.x * 4 + wid;   // global wave id
    const int nw = gridDim.x * 4;

    for (int tile = gw; tile < ntiles; tile += nw) {
        const int rowbase = tile * 16;
        const float* xt = x + (size_t)rowbase * DIM;

        // ---- A-fragments straight from global (coalesced, HBM 1x) ----
        // A-frag: lane holds A[m][k], m = l15, k = quad*8+j (+32 for half 1).
        bf16x8 a0, a1;
        {
            const float* p = xt + l15 * DIM + quad * 8;
            f32x4 u0 = *(const f32x4*)(p);
            f32x4 u1 = *(const f32x4*)(p + 4);
            f32x4 v0 = *(const f32x4*)(p + 32);
            f32x4 v1 = *(const f32x4*)(p + 36);
            #pragma unroll
            for (int j = 0; j < 4; ++j) {
                a0[j]     = (__bf16)u0[j];
                a0[j + 4] = (__bf16)u1[j];
                a1[j]     = (__bf16)v0[j];
                a1[j + 4] = (__bf16)v1[j];
            }
        }

        float qacc[4] = {0.f, 0.f, 0.f, 0.f};
        float nacc[4] = {0.f, 0.f, 0.f, 0.f};

        #pragma unroll
        for (int t = 0; t < 4; ++t) {
            f32x4 acc = {0.f, 0.f, 0.f, 0.f};
            acc = __builtin_amdgcn_mfma_f32_16x16x32_bf16(a0, bfrag[t][0], acc, 0, 0, 0);
            acc = __builtin_amdgcn_mfma_f32_16x16x32_bf16(a1, bfrag[t][1], acc, 0, 0, 0);
            // C-layout: acc[r] = Y[row = quad*4 + r][col = t*16 + l15]  (measured m89/m91)
            #pragma unroll
            for (int r = 0; r < 4; ++r) {
                float xv = xt[(quad * 4 + r) * DIM + t * 16 + l15];  // L1 hit (tile just fetched)
                qacc[r] += xv * acc[r];
                nacc[r] += xv * xv;
            }
        }

        // ---- reduce over the 16 lanes of each quarter-wave ----
        #pragma unroll
        for (int m = 1; m < 16; m <<= 1) {
            #pragma unroll
            for (int r = 0; r < 4; ++r) {
                qacc[r] += __shfl_xor(qacc[r], m, 64);
                nacc[r] += __shfl_xor(nacc[r], m, 64);
            }
        }

        if (l15 == 0) {
            f32x4 o;
            #pragma unroll
            for (int r = 0; r < 4; ++r) o[r] = qacc[r] * nacc[r];
            *(f32x4*)(out + rowbase + quad * 4) = o;  // rows quad*4..quad*4+3
        }
    }
}

extern "C" void kernel_launch(void* const* d_in, const int* in_sizes, int n_in,
                              void* d_out, int out_size, void* d_ws, size_t ws_size,
                              hipStream_t stream) {
    const float* x   = (const float*)d_in[0];
    const float* rho = (const float*)d_in[1];
    float* out = (float*)d_out;

    const int batch  = in_sizes[0] / DIM;   // 4194304
    const int ntiles = batch / 16;          // 262144 (batch divisible by 16)

    // 2048 blocks x 4 waves = 8192 waves, grid-stride over 262144 tiles
    // (32 tiles/wave) -> rho fragment loads amortized, grid saturates 256 CUs.
    qim_kernel<<<2048, 256, 0, stream>>>(x, rho, out, ntiles);
}